// Round 12
// baseline (328.889 us; speedup 1.0000x reference)
//
#include <hip/hip_runtime.h>
#include <hip/hip_fp8.h>

typedef unsigned short u16;
typedef unsigned char u8;
typedef unsigned int u32;
typedef short bf16x8 __attribute__((ext_vector_type(8)));
typedef float f32x4 __attribute__((ext_vector_type(4)));
typedef u16 u16x4 __attribute__((ext_vector_type(4)));
typedef int i32x8 __attribute__((ext_vector_type(8)));
typedef long l64x4 __attribute__((ext_vector_type(4)));

#define SCALE_Q 0.044194173824159216f   // 1/sqrt(512)

// barrier WITHOUT vmcnt drain (lgkm only): in-flight global/DMA ops survive.
#define BAR() asm volatile("s_waitcnt lgkmcnt(0)\n\ts_barrier" ::: "memory")

__device__ __forceinline__ u16 f2b(float f){   // fp32 -> bf16 RNE
  unsigned u = __float_as_uint(f);
  u += 0x7fffu + ((u >> 16) & 1u);
  return (u16)(u >> 16);
}

__device__ __forceinline__ u8 f2e4(float f){   // fp32 -> fp8 e4m3 (OCP)
  return __hip_fp8_e4m3(f).__x;
}

__device__ __forceinline__ u32 pk4e4(float e0, float e1, float e2, float e3){
#if defined(__has_builtin) && __has_builtin(__builtin_amdgcn_cvt_pk_fp8_f32)
  int pk = __builtin_amdgcn_cvt_pk_fp8_f32(e0, e1, 0, false);
  pk = __builtin_amdgcn_cvt_pk_fp8_f32(e2, e3, pk, true);
  return (u32)pk;
#else
  return (u32)f2e4(e0) | ((u32)f2e4(e1) << 8)
       | ((u32)f2e4(e2) << 16) | ((u32)f2e4(e3) << 24);
#endif
}

__device__ __forceinline__ void gload16(const void* g, void* l){
  __builtin_amdgcn_global_load_lds(
      (const __attribute__((address_space(1))) void*)g,
      (__attribute__((address_space(3))) void*)l, 16, 0, 0);
}

// ---------------- GroupNorm stats: one block per (b, group) ----------------
__global__ __launch_bounds__(256) void gn_stats(const float* __restrict__ x,
                                                float* __restrict__ stats){
  int bg = blockIdx.x;
  const float4* p4 = (const float4*)(x + (size_t)bg * 65536);
  float s = 0.f, ss = 0.f;
  for (int i = threadIdx.x; i < 16384; i += 256){
    float4 v = p4[i];
    s  += v.x + v.y + v.z + v.w;
    ss += v.x*v.x + v.y*v.y + v.z*v.z + v.w*v.w;
  }
  for (int off = 32; off; off >>= 1){
    s  += __shfl_down(s, off);
    ss += __shfl_down(ss, off);
  }
  __shared__ float as_[4], bs_[4];
  int wid = threadIdx.x >> 6, lid = threadIdx.x & 63;
  if (lid == 0){ as_[wid] = s; bs_[wid] = ss; }
  __syncthreads();
  if (threadIdx.x == 0){
    float S = as_[0]+as_[1]+as_[2]+as_[3], SS = bs_[0]+bs_[1]+bs_[2]+bs_[3];
    float mean = S * (1.f/65536.f);
    float var  = SS * (1.f/65536.f) - mean*mean;
    stats[2*bg]   = mean;
    stats[2*bg+1] = rsqrtf(var + 1e-6f);
  }
}

// ------- normalize + affine + transpose [b,c,N] -> t[b,N,c] (bf16) ---------
__global__ __launch_bounds__(256) void gn_apply_T(const float* __restrict__ x,
                                                  const float* __restrict__ stats,
                                                  const float* __restrict__ gamma,
                                                  const float* __restrict__ beta,
                                                  u16* __restrict__ t){
  __shared__ float tile[32][33];
  int nb = blockIdx.x, cb = blockIdx.y, b = blockIdx.z;
  int tx = threadIdx.x & 31, ty = threadIdx.x >> 5;
  int n0 = nb * 32, c0 = cb * 32;
  #pragma unroll
  for (int i = 0; i < 4; i++){
    int ch = c0 + ty + i*8;
    float mean = stats[2*((b<<5) + (ch>>4))];
    float rstd = stats[2*((b<<5) + (ch>>4)) + 1];
    float v = x[(((size_t)b*512 + ch) << 12) + n0 + tx];
    tile[ty + i*8][tx] = (v - mean) * rstd * gamma[ch] + beta[ch];
  }
  __syncthreads();
  #pragma unroll
  for (int i = 0; i < 4; i++){
    int n = n0 + ty + i*8;
    int ch = c0 + tx;
    t[((size_t)((b<<12) + n))*512 + ch] = f2b(tile[tx][ty + i*8]);
  }
}

// ---------------- fp32 -> bf16 weight conversion (4 matrices) --------------
__global__ __launch_bounds__(256) void w2bf(const float* __restrict__ a,
                                            const float* __restrict__ b,
                                            const float* __restrict__ c,
                                            const float* __restrict__ d,
                                            u16* __restrict__ o){
  int idx = blockIdx.x * 256 + threadIdx.x;
  int which = idx >> 16;
  const float4* src = (const float4*)(which == 0 ? a : which == 1 ? b : which == 2 ? c : d);
  float4 v = src[idx & 65535];
  u16x4 pk;
  pk.x = f2b(v.x); pk.y = f2b(v.y); pk.z = f2b(v.z); pk.w = f2b(v.w);
  *(u16x4*)(o + (size_t)idx*4) = pk;
}

// ------------- fused QKV gemm: grid (128, 12); y>>2 selects matrix ---------
// mat 0 -> Q fp8 e4m3 [b,tok,c] (unscaled), staged through LDS (coalesced)
// mat 1 -> K fp8 tiled [b][tile64][ks16][kr64][ch32], chunk swz = q4^((kr>>2)&3)
// mat 2 -> V fp8 tiled [b][tile64][c512][kv64], chunk swz = chunk^(n&7)
// All epilogues staged through LDS -> coalesced dwordx4 global stores.
// launch_bounds (256,4): 4 resident blocks/CU (no spill; verified R10).
__global__ __launch_bounds__(256, 4) void qkv_gemm(const u16* __restrict__ A,
                                                   const u16* __restrict__ Wcat,
                                                   const float* __restrict__ qbias,
                                                   const float* __restrict__ kbias,
                                                   const float* __restrict__ vbias,
                                                   u8* __restrict__ qo,
                                                   u8* __restrict__ ko,
                                                   u8* __restrict__ vo){
  __shared__ __align__(16) u16 SMEM[8192];     // As | Bs, reused as 16KB stage
  u16* As = SMEM;
  u16* Bs = SMEM + 4096;
  const int t = threadIdx.x;
  const int w = t >> 6, ln = t & 63;
  const int wr = w >> 1, wc = w & 1;
  const int q4 = ln >> 4, l15 = ln & 15;
  const int y = blockIdx.y;
  const int mat = y >> 2, yb = y & 3;
  const int row0 = blockIdx.x * 128;
  const u16* Ab = A    + (size_t)row0 * 512;
  const u16* Bb = Wcat + (size_t)y * 128 * 512;
  f32x4 acc[4][4];
  #pragma unroll
  for (int i = 0; i < 4; i++)
    #pragma unroll
    for (int j = 0; j < 4; j++){
      acc[i][j][0]=0.f; acc[i][j][1]=0.f; acc[i][j][2]=0.f; acc[i][j][3]=0.f;
    }
  for (int kt = 0; kt < 16; ++kt){
    #pragma unroll
    for (int i = 0; i < 2; i++){
      int idx = i*256 + t;
      gload16(Ab + (size_t)(idx>>2)*512 + kt*32 + (idx&3)*8, As + (size_t)idx*8);
      gload16(Bb + (size_t)(idx>>2)*512 + kt*32 + (idx&3)*8, Bs + (size_t)idx*8);
    }
    __syncthreads();
    bf16x8 af[4], bf[4];
    #pragma unroll
    for (int mt = 0; mt < 4; mt++)
      af[mt] = *(const bf16x8*)(As + (wr*64 + mt*16 + l15)*32 + q4*8);
    #pragma unroll
    for (int nt = 0; nt < 4; nt++)
      bf[nt] = *(const bf16x8*)(Bs + (wc*64 + nt*16 + l15)*32 + q4*8);
    #pragma unroll
    for (int mt = 0; mt < 4; mt++)
      #pragma unroll
      for (int nt = 0; nt < 4; nt++)
        acc[mt][nt] = __builtin_amdgcn_mfma_f32_16x16x32_bf16(af[mt], bf[nt], acc[mt][nt], 0, 0, 0);
    __syncthreads();
  }
  const int bb = row0 >> 12;            // batch
  const int tile0 = (row0 >> 6) & 63;   // first 64-token tile of this block
  const int col0 = yb*128 + wc*64;      // global channel base for this wave
  u8* Ls = (u8*)SMEM;                   // 16KB staging

  if (mat == 0){
    // stage Q fp8 tile [128 rows][128 cols] into LDS, then coalesced stores
    #pragma unroll
    for (int nt = 0; nt < 4; nt++){
      int n = col0 + nt*16 + l15;
      float bv = qbias[n];
      int cloc = wc*64 + nt*16 + l15;
      #pragma unroll
      for (int mt = 0; mt < 4; mt++){
        int rloc = wr*64 + mt*16 + q4*4;
        #pragma unroll
        for (int r = 0; r < 4; r++)
          Ls[(rloc + r)*128 + cloc] = f2e4(acc[mt][nt][r] + bv);
      }
    }
    __syncthreads();
    #pragma unroll
    for (int i = 0; i < 4; i++){
      int ci = i*256 + t;                    // 16B chunk 0..1023
      u8* dst = qo + (size_t)(row0 + (ci >> 3))*512 + yb*128 + (ci & 7)*16;
      *(float4*)dst = *(const float4*)(Ls + (size_t)ci*16);
    }
  } else if (mat == 1){
    // stage into LDS in exact global within-tile layout
    #pragma unroll
    for (int nt = 0; nt < 4; nt++){
      int n = col0 + nt*16 + l15;
      float bv = kbias[n];
      int ksl = wc*2 + (nt >> 1);            // block-local ks (0..3)
      int c3  = ((nt & 1)*2 + (l15 >> 3));   // ch>>3 within 32-ch group
      #pragma unroll
      for (int mt = 0; mt < 4; mt++){
        #pragma unroll
        for (int r = 0; r < 4; r++){
          int kr = mt*16 + q4*4 + r;
          int chunk = c3 ^ ((kr >> 2) & 3);
          Ls[(wr*4 + ksl)*2048 + kr*32 + chunk*8 + (l15 & 7)] = f2e4(acc[mt][nt][r] + bv);
        }
      }
    }
    __syncthreads();
    #pragma unroll
    for (int i = 0; i < 4; i++){
      int ci = i*256 + t;                    // 16B chunk 0..1023
      int ri = ci >> 7, t2 = ri >> 2, ksl2 = ri & 3;
      u8* dst = ko + ((size_t)(bb*64 + tile0 + t2))*32768
                   + (size_t)(yb*4 + ksl2)*2048 + (size_t)(ci & 127)*16;
      *(float4*)dst = *(const float4*)(Ls + (size_t)ci*16);
    }
  } else {
    #pragma unroll
    for (int nt = 0; nt < 4; nt++){
      int n = col0 + nt*16 + l15;
      float bv = vbias[n];
      int nl = n & 127;
      #pragma unroll
      for (int mt = 0; mt < 4; mt++){
        int kv = mt*16 + q4*4;
        u32 pk = (u32)f2e4(acc[mt][nt][0] + bv)
               | ((u32)f2e4(acc[mt][nt][1] + bv) << 8)
               | ((u32)f2e4(acc[mt][nt][2] + bv) << 16)
               | ((u32)f2e4(acc[mt][nt][3] + bv) << 24);
        int phys = (kv >> 3) ^ (n & 7);
        *(u32*)(Ls + wr*8192 + nl*64 + phys*8 + (kv & 4)) = pk;
      }
    }
    __syncthreads();
    #pragma unroll
    for (int i = 0; i < 4; i++){
      int ci = i*256 + t;                    // 16B chunk 0..1023
      int t2 = ci >> 9;
      u8* dst = vo + ((size_t)(bb*64 + tile0 + t2))*32768
                   + (size_t)yb*8192 + (size_t)(ci & 511)*16;
      *(float4*)dst = *(const float4*)(Ls + (size_t)ci*16);
    }
  }
}

// ----------- out-proj gemm + bias + residual + transpose (fp32 out) --------
__global__ __launch_bounds__(256, 2) void out_gemm(const u16* __restrict__ A,
                                                   const u16* __restrict__ Bw,
                                                   const float* __restrict__ bias,
                                                   float* __restrict__ out,
                                                   const float* __restrict__ resid){
  __shared__ __align__(16) u16 As[128*32];
  __shared__ __align__(16) u16 Bs[128*32];
  const int t = threadIdx.x;
  const int w = t >> 6, ln = t & 63;
  const int wr = w >> 1, wc = w & 1;
  const int q4 = ln >> 4, l15 = ln & 15;
  const u16* Ab = A  + (size_t)blockIdx.x * 128 * 512;
  const u16* Bb = Bw + (size_t)blockIdx.y * 128 * 512;
  f32x4 acc[4][4];
  #pragma unroll
  for (int i = 0; i < 4; i++)
    #pragma unroll
    for (int j = 0; j < 4; j++){
      acc[i][j][0]=0.f; acc[i][j][1]=0.f; acc[i][j][2]=0.f; acc[i][j][3]=0.f;
    }
  for (int kt = 0; kt < 16; ++kt){
    #pragma unroll
    for (int i = 0; i < 2; i++){
      int idx = i*256 + t;
      gload16(Ab + (size_t)(idx>>2)*512 + kt*32 + (idx&3)*8, As + (size_t)idx*8);
      gload16(Bb + (size_t)(idx>>2)*512 + kt*32 + (idx&3)*8, Bs + (size_t)idx*8);
    }
    __syncthreads();
    bf16x8 af[4], bf[4];
    #pragma unroll
    for (int mt = 0; mt < 4; mt++)
      af[mt] = *(const bf16x8*)(As + (wr*64 + mt*16 + l15)*32 + q4*8);
    #pragma unroll
    for (int nt = 0; nt < 4; nt++)
      bf[nt] = *(const bf16x8*)(Bs + (wc*64 + nt*16 + l15)*32 + q4*8);
    #pragma unroll
    for (int mt = 0; mt < 4; mt++)
      #pragma unroll
      for (int nt = 0; nt < 4; nt++)
        acc[mt][nt] = __builtin_amdgcn_mfma_f32_16x16x32_bf16(af[mt], bf[nt], acc[mt][nt], 0, 0, 0);
    __syncthreads();
  }
  const int row0 = blockIdx.x*128 + wr*64;
  const int col0 = blockIdx.y*128 + wc*64;
  #pragma unroll
  for (int nt = 0; nt < 4; nt++){
    int n = col0 + nt*16 + l15;
    float bv = bias[n];
    #pragma unroll
    for (int mt = 0; mt < 4; mt++){
      int m0 = row0 + mt*16 + q4*4;
      int bb = m0 >> 12, tok = m0 & 4095;
      size_t base = (((size_t)(bb*512 + n)) << 12) + tok;
      float4 xr = *(const float4*)(resid + base);
      float4 ov;
      ov.x = acc[mt][nt][0] + bv + xr.x;
      ov.y = acc[mt][nt][1] + bv + xr.y;
      ov.z = acc[mt][nt][2] + bv + xr.z;
      ov.w = acc[mt][nt][3] + bv + xr.w;
      *(float4*)(out + base) = ov;
    }
  }
}

// ---------------------------- flash attention ------------------------------
// q fp8 [b,tok,512]; kt fp8 tiled [b][64][ks16][kr64][ch32] (swizzled);
// vt fp8 tiled [b][64][c512][kv64] (swizzled); out O bf16 [b,tok,512].
// BM=32, BN=64, 256 threads (4 waves), 2 blocks/CU, 64 iterations.
// V loads issued BEFORE K-DMA (R10: PV wait = vmcnt(8), DMA in flight thru PV).
// S via MX-scaled mfma_scale 16x16x128 with UNIT scales (== plain fp8 dot at
// 2.25x rate, m21): 8 S-MFMAs/wave instead of 32. Operands SWAPPED (A=K, B=Q)
// so lane (q4,l15) holds S[q=rt*16+l15][kv=chh*32(+16)+q4*4+r] — same output
// layout as R11's swapped K=32 version (verified R4/R5/R11); softmax, packed
// P-writes, PV, and epilogue are byte-identical. (256,2) => 256-VGPR cap; R4's
// spill was at a 128 cap — watch WRITE_SIZE (must stay 16384).
// NOTE: no s_setprio — measured -5% in this lockstep-barrier regime (R8).
__global__ __launch_bounds__(256, 2) void attn_fwd(const u8* __restrict__ q,
                                                   const u8* __restrict__ kt,
                                                   const u8* __restrict__ vt,
                                                   u16* __restrict__ outO){
  __shared__ __align__(16) u8 Kb[2][32768];    // 2 x 32KB fp8 K tiles
  __shared__ __align__(16) u8 Pb[32*72];       // P fp8 [qrow32][kv64 +8 pad]
  __shared__ __align__(16) float lL[64];       // [chh][row32]

  const int t = threadIdx.x, w = t >> 6, ln = t & 63;
  const int q4 = ln >> 4, l15 = ln & 15;
  const int rt = w >> 1, chh = w & 1;          // S role: row-tile, col-half
  const int b = blockIdx.y, q0 = blockIdx.x * 32;
  const u8* kbase = kt + ((size_t)b << 21);
  const u8* vbase = vt + ((size_t)b << 21);

  // Q fragments for MX K=128: qm[kk] = Q[row][kk*128 + q4*32 .. +32] (32 VGPR)
  i32x8 qm[4];
  {
    const u8* qr = q + (size_t)((b<<12) + q0 + rt*16 + l15) * 512;
    #pragma unroll
    for (int kk = 0; kk < 4; kk++)
      qm[kk] = *(const i32x8*)(qr + kk*128 + q4*32);
  }
  f32x4 oacc[2][8];
  #pragma unroll
  for (int i = 0; i < 2; i++)
    #pragma unroll
    for (int j = 0; j < 8; j++){
      oacc[i][j][0]=0.f; oacc[i][j][1]=0.f; oacc[i][j][2]=0.f; oacc[i][j][3]=0.f;
    }
  float lrow = 0.f;

  // K fragment offsets: per kv-tile (kr0/kr1), 4 swizzled 8B chunks per
  // ks-block; ks = kk*4 + q4 -> LDS offset kk*8192 + q4*2048 + chunk.
  const int kr0 = chh*32 + l15,  kr1 = chh*32 + 16 + l15;
  const int sw0 = (kr0 >> 2) & 3, sw1 = (kr1 >> 2) & 3;
  int kofA[4], kofB[4];
  #pragma unroll
  for (int c = 0; c < 4; c++){
    kofA[c] = q4*2048 + kr0*32 + ((c ^ sw0) << 3);
    kofB[c] = q4*2048 + kr1*32 + ((c ^ sw1) << 3);
  }

  // prologue: DMA K tile 0 into Kb[0] (2048 x 16B chunks, 8 per thread)
  #pragma unroll
  for (int i = 0; i < 8; i++){
    int ci = i*256 + t;
    gload16(kbase + (size_t)ci*16, &Kb[0][ci*16]);
  }
  __syncthreads();

  #pragma unroll 1
  for (int j = 0; j < 64; ++j){
    // 1. V fragment loads from L2 EARLY (issued FIRST so the PV wait is
    //    vmcnt(8), leaving the K-DMA in flight through PV)
    long vf0[8], vf1[8];
    {
      const u8* vtile = vbase + ((size_t)j << 15);
      #pragma unroll
      for (int ct = 0; ct < 8; ct++){
        int ch = 128*w + ct*16 + l15;
        int swz = ch & 7;
        const u8* vr = vtile + (size_t)ch*64;
        vf0[ct] = *(const long*)(vr + ((q4 ^ swz) << 3));
        vf1[ct] = *(const long*)(vr + (((4 + q4) ^ swz) << 3));
      }
    }
    // 2. issue DMA for K tile j+1 (other buffer; drains at end-of-iter sync)
    {
      const u8* kn = kbase + ((size_t)((j + 1) & 63) << 15);
      u8* kd = Kb[(j + 1) & 1];
      #pragma unroll
      for (int i = 0; i < 8; i++){
        int ci = i*256 + t;
        gload16(kn + (size_t)ci*16, kd + ci*16);
      }
    }
    // 3. S^T = K Q^T via MX-scaled K=128 fp8, unit scales: 2 kv-tiles x
    //    (even/odd kk chains) = 8 MFMAs. Same output layout as R11.
    const u8* Kp = Kb[j & 1];
    f32x4 sA0, sA1, sB0, sB1;
    sA0[0]=0.f;sA0[1]=0.f;sA0[2]=0.f;sA0[3]=0.f;
    sA1[0]=0.f;sA1[1]=0.f;sA1[2]=0.f;sA1[3]=0.f;
    sB0[0]=0.f;sB0[1]=0.f;sB0[2]=0.f;sB0[3]=0.f;
    sB1[0]=0.f;sB1[1]=0.f;sB1[2]=0.f;sB1[3]=0.f;
    #pragma unroll
    for (int kk = 0; kk < 4; kk++){
      const u8* e = Kp + kk*8192;
      l64x4 la, lb;
      la[0] = *(const long*)(e + kofA[0]);
      la[1] = *(const long*)(e + kofA[1]);
      la[2] = *(const long*)(e + kofA[2]);
      la[3] = *(const long*)(e + kofA[3]);
      lb[0] = *(const long*)(e + kofB[0]);
      lb[1] = *(const long*)(e + kofB[1]);
      lb[2] = *(const long*)(e + kofB[2]);
      lb[3] = *(const long*)(e + kofB[3]);
      i32x8 ka = __builtin_bit_cast(i32x8, la);
      i32x8 kb = __builtin_bit_cast(i32x8, lb);
      if (kk & 1){
        sA1 = __builtin_amdgcn_mfma_scale_f32_16x16x128_f8f6f4(
                  ka, qm[kk], sA1, 0, 0, 0, 0x7F, 0, 0x7F);
        sB1 = __builtin_amdgcn_mfma_scale_f32_16x16x128_f8f6f4(
                  kb, qm[kk], sB1, 0, 0, 0, 0x7F, 0, 0x7F);
      } else {
        sA0 = __builtin_amdgcn_mfma_scale_f32_16x16x128_f8f6f4(
                  ka, qm[kk], sA0, 0, 0, 0, 0x7F, 0, 0x7F);
        sB0 = __builtin_amdgcn_mfma_scale_f32_16x16x128_f8f6f4(
                  kb, qm[kk], sB0, 0, 0, 0, 0x7F, 0, 0x7F);
      }
    }
    // 4. max-free softmax -> P fp8 in LDS (packed u32 writes; same bytes,
    //    same addresses as before)
    {
      float a0 = __expf((sA0[0] + sA1[0]) * SCALE_Q);
      float a1 = __expf((sA0[1] + sA1[1]) * SCALE_Q);
      float a2 = __expf((sA0[2] + sA1[2]) * SCALE_Q);
      float a3 = __expf((sA0[3] + sA1[3]) * SCALE_Q);
      float b0 = __expf((sB0[0] + sB1[0]) * SCALE_Q);
      float b1 = __expf((sB0[1] + sB1[1]) * SCALE_Q);
      float b2 = __expf((sB0[2] + sB1[2]) * SCALE_Q);
      float b3 = __expf((sB0[3] + sB1[3]) * SCALE_Q);
      lrow += ((a0 + a1) + (a2 + a3)) + ((b0 + b1) + (b2 + b3));
      u8* Pw = Pb + (rt*16 + l15)*72 + chh*32 + q4*4;
      *(u32*)(Pw)      = pk4e4(a0, a1, a2, a3);
      *(u32*)(Pw + 16) = pk4e4(b0, b1, b2, b3);
    }
    BAR();                                   // P visible; DMA + vf in flight
    // 5. PV (fp8): O += P V ; wave owns col strip [128w, 128w+128)
    {
      long pf00 = *(const long*)(Pb + l15*72 + q4*8);
      long pf01 = *(const long*)(Pb + l15*72 + 32 + q4*8);
      long pf10 = *(const long*)(Pb + (16 + l15)*72 + q4*8);
      long pf11 = *(const long*)(Pb + (16 + l15)*72 + 32 + q4*8);
      #pragma unroll
      for (int ct = 0; ct < 8; ct++){
        f32x4 a0 = oacc[0][ct], a1 = oacc[1][ct];
        a0 = __builtin_amdgcn_mfma_f32_16x16x32_fp8_fp8(pf00, vf0[ct], a0, 0, 0, 0);
        a1 = __builtin_amdgcn_mfma_f32_16x16x32_fp8_fp8(pf10, vf0[ct], a1, 0, 0, 0);
        a0 = __builtin_amdgcn_mfma_f32_16x16x32_fp8_fp8(pf01, vf1[ct], a0, 0, 0, 0);
        a1 = __builtin_amdgcn_mfma_f32_16x16x32_fp8_fp8(pf11, vf1[ct], a1, 0, 0, 0);
        oacc[0][ct] = a0; oacc[1][ct] = a1;
      }
    }
    __syncthreads();                         // drains DMA(j+1) before S(j+1)
  }

  // ---- epilogue: reduce l across q4 groups + the two col-half waves ----
  {
    float v = lrow;
    v += __shfl_xor(v, 16);
    v += __shfl_xor(v, 32);
    if (ln < 16) lL[chh*32 + rt*16 + ln] = v;
  }
  __syncthreads();
  #pragma unroll
  for (int rr = 0; rr < 2; rr++){
    #pragma unroll
    for (int r = 0; r < 4; r++){
      int row = rr*16 + q4*4 + r;
      float inv = 1.f / (lL[row] + lL[32 + row]);
      u16* op = outO + ((size_t)b << 21) + (size_t)(q0 + row)*512 + 128*w + l15;
      #pragma unroll
      for (int ct = 0; ct < 8; ct++)
        op[ct*16] = f2b(oacc[rr][ct][r] * inv);
    }
  }
}

extern "C" void kernel_launch(void* const* d_in, const int* in_sizes, int n_in,
                              void* d_out, int out_size, void* d_ws, size_t ws_size,
                              hipStream_t stream){
  const float* x     = (const float*)d_in[0];
  const float* gamma = (const float*)d_in[1];
  const float* beta  = (const float*)d_in[2];
  const float* wq_w  = (const float*)d_in[3];
  const float* wq_b  = (const float*)d_in[4];
  const float* wk_w  = (const float*)d_in[5];
  const float* wk_b  = (const float*)d_in[6];
  const float* wv_w  = (const float*)d_in[7];
  const float* wv_b  = (const float*)d_in[8];
  const float* out_w = (const float*)d_in[9];
  const float* out_b = (const float*)d_in[10];

  char* ws = (char*)d_ws;
  float* stats = (float*)ws;                                   // 1 KB
  u16* tbuf = (u16*)(ws + 4096);                               // 16 MB (t, then O)
  size_t off = 4096 + (size_t)16*1024*1024;
  u16* Wcat = (u16*)(ws + off); off += (size_t)4*512*512*2;    // 2 MB
  u8*  qb   = (u8*)(ws + off);  off += (size_t)16*1024*1024;   // Q fp8
  u8*  ktb  = (u8*)(ws + off);  off += (size_t)16*1024*1024;   // K fp8 tiled
  u8*  vtb  = (u8*)(ws + off);  off += (size_t)16*1024*1024;   // V fp8 tiled

  gn_stats<<<128, 256, 0, stream>>>(x, stats);
  gn_apply_T<<<dim3(128, 16, 4), 256, 0, stream>>>(x, stats, gamma, beta, tbuf);
  w2bf<<<1024, 256, 0, stream>>>(wq_w, wk_w, wv_w, out_w, Wcat);
  u16* Wo = Wcat + 3*512*512;
  qkv_gemm<<<dim3(128, 12), 256, 0, stream>>>(tbuf, Wcat, wq_b, wk_b, wv_b,
                                              qb, ktb, vtb);
  attn_fwd<<<dim3(128, 4), 256, 0, stream>>>(qb, ktb, vtb, tbuf);
  out_gemm<<<dim3(128, 4), 256, 0, stream>>>(tbuf, Wo, out_b, (float*)d_out, x);
}

// Round 13
// 324.703 us; speedup vs baseline: 1.0129x; 1.0129x over previous
//
#include <hip/hip_runtime.h>
#include <hip/hip_fp8.h>

typedef unsigned short u16;
typedef unsigned char u8;
typedef unsigned int u32;
typedef short bf16x8 __attribute__((ext_vector_type(8)));
typedef float f32x4 __attribute__((ext_vector_type(4)));
typedef u16 u16x4 __attribute__((ext_vector_type(4)));

#define SCALE_Q 0.044194173824159216f   // 1/sqrt(512)

// barrier WITHOUT vmcnt drain (lgkm only): in-flight global/DMA ops survive.
#define BAR() asm volatile("s_waitcnt lgkmcnt(0)\n\ts_barrier" ::: "memory")

__device__ __forceinline__ u16 f2b(float f){   // fp32 -> bf16 RNE
  unsigned u = __float_as_uint(f);
  u += 0x7fffu + ((u >> 16) & 1u);
  return (u16)(u >> 16);
}

__device__ __forceinline__ u8 f2e4(float f){   // fp32 -> fp8 e4m3 (OCP)
  return __hip_fp8_e4m3(f).__x;
}

__device__ __forceinline__ u32 pk4e4(float e0, float e1, float e2, float e3){
#if defined(__has_builtin) && __has_builtin(__builtin_amdgcn_cvt_pk_fp8_f32)
  int pk = __builtin_amdgcn_cvt_pk_fp8_f32(e0, e1, 0, false);
  pk = __builtin_amdgcn_cvt_pk_fp8_f32(e2, e3, pk, true);
  return (u32)pk;
#else
  return (u32)f2e4(e0) | ((u32)f2e4(e1) << 8)
       | ((u32)f2e4(e2) << 16) | ((u32)f2e4(e3) << 24);
#endif
}

__device__ __forceinline__ void gload16(const void* g, void* l){
  __builtin_amdgcn_global_load_lds(
      (const __attribute__((address_space(1))) void*)g,
      (__attribute__((address_space(3))) void*)l, 16, 0, 0);
}

// ---------------- GroupNorm stats: one block per (b, group) ----------------
__global__ __launch_bounds__(256) void gn_stats(const float* __restrict__ x,
                                                float* __restrict__ stats){
  int bg = blockIdx.x;
  const float4* p4 = (const float4*)(x + (size_t)bg * 65536);
  float s = 0.f, ss = 0.f;
  for (int i = threadIdx.x; i < 16384; i += 256){
    float4 v = p4[i];
    s  += v.x + v.y + v.z + v.w;
    ss += v.x*v.x + v.y*v.y + v.z*v.z + v.w*v.w;
  }
  for (int off = 32; off; off >>= 1){
    s  += __shfl_down(s, off);
    ss += __shfl_down(ss, off);
  }
  __shared__ float as_[4], bs_[4];
  int wid = threadIdx.x >> 6, lid = threadIdx.x & 63;
  if (lid == 0){ as_[wid] = s; bs_[wid] = ss; }
  __syncthreads();
  if (threadIdx.x == 0){
    float S = as_[0]+as_[1]+as_[2]+as_[3], SS = bs_[0]+bs_[1]+bs_[2]+bs_[3];
    float mean = S * (1.f/65536.f);
    float var  = SS * (1.f/65536.f) - mean*mean;
    stats[2*bg]   = mean;
    stats[2*bg+1] = rsqrtf(var + 1e-6f);
  }
}

// ------- normalize + affine + transpose [b,c,N] -> t[b,N,c] (bf16) ---------
__global__ __launch_bounds__(256) void gn_apply_T(const float* __restrict__ x,
                                                  const float* __restrict__ stats,
                                                  const float* __restrict__ gamma,
                                                  const float* __restrict__ beta,
                                                  u16* __restrict__ t){
  __shared__ float tile[32][33];
  int nb = blockIdx.x, cb = blockIdx.y, b = blockIdx.z;
  int tx = threadIdx.x & 31, ty = threadIdx.x >> 5;
  int n0 = nb * 32, c0 = cb * 32;
  #pragma unroll
  for (int i = 0; i < 4; i++){
    int ch = c0 + ty + i*8;
    float mean = stats[2*((b<<5) + (ch>>4))];
    float rstd = stats[2*((b<<5) + (ch>>4)) + 1];
    float v = x[(((size_t)b*512 + ch) << 12) + n0 + tx];
    tile[ty + i*8][tx] = (v - mean) * rstd * gamma[ch] + beta[ch];
  }
  __syncthreads();
  #pragma unroll
  for (int i = 0; i < 4; i++){
    int n = n0 + ty + i*8;
    int ch = c0 + tx;
    t[((size_t)((b<<12) + n))*512 + ch] = f2b(tile[tx][ty + i*8]);
  }
}

// ---------------- fp32 -> bf16 weight conversion (4 matrices) --------------
__global__ __launch_bounds__(256) void w2bf(const float* __restrict__ a,
                                            const float* __restrict__ b,
                                            const float* __restrict__ c,
                                            const float* __restrict__ d,
                                            u16* __restrict__ o){
  int idx = blockIdx.x * 256 + threadIdx.x;
  int which = idx >> 16;
  const float4* src = (const float4*)(which == 0 ? a : which == 1 ? b : which == 2 ? c : d);
  float4 v = src[idx & 65535];
  u16x4 pk;
  pk.x = f2b(v.x); pk.y = f2b(v.y); pk.z = f2b(v.z); pk.w = f2b(v.w);
  *(u16x4*)(o + (size_t)idx*4) = pk;
}

// ------------- fused QKV gemm: grid (128, 12); y>>2 selects matrix ---------
// mat 0 -> Q fp8 e4m3 [b,tok,c] (unscaled), staged through LDS (coalesced)
// mat 1 -> K fp8 tiled [b][tile64][ks16][kr64][ch32], chunk swz = q4^((kr>>2)&3)
// mat 2 -> V fp8 tiled [b][tile64][c512][kv64], chunk swz = chunk^(n&7)
// All epilogues staged through LDS -> coalesced dwordx4 global stores.
// launch_bounds (256,4): 4 resident blocks/CU (no spill; verified R10).
__global__ __launch_bounds__(256, 4) void qkv_gemm(const u16* __restrict__ A,
                                                   const u16* __restrict__ Wcat,
                                                   const float* __restrict__ qbias,
                                                   const float* __restrict__ kbias,
                                                   const float* __restrict__ vbias,
                                                   u8* __restrict__ qo,
                                                   u8* __restrict__ ko,
                                                   u8* __restrict__ vo){
  __shared__ __align__(16) u16 SMEM[8192];     // As | Bs, reused as 16KB stage
  u16* As = SMEM;
  u16* Bs = SMEM + 4096;
  const int t = threadIdx.x;
  const int w = t >> 6, ln = t & 63;
  const int wr = w >> 1, wc = w & 1;
  const int q4 = ln >> 4, l15 = ln & 15;
  const int y = blockIdx.y;
  const int mat = y >> 2, yb = y & 3;
  const int row0 = blockIdx.x * 128;
  const u16* Ab = A    + (size_t)row0 * 512;
  const u16* Bb = Wcat + (size_t)y * 128 * 512;
  f32x4 acc[4][4];
  #pragma unroll
  for (int i = 0; i < 4; i++)
    #pragma unroll
    for (int j = 0; j < 4; j++){
      acc[i][j][0]=0.f; acc[i][j][1]=0.f; acc[i][j][2]=0.f; acc[i][j][3]=0.f;
    }
  for (int kt = 0; kt < 16; ++kt){
    #pragma unroll
    for (int i = 0; i < 2; i++){
      int idx = i*256 + t;
      gload16(Ab + (size_t)(idx>>2)*512 + kt*32 + (idx&3)*8, As + (size_t)idx*8);
      gload16(Bb + (size_t)(idx>>2)*512 + kt*32 + (idx&3)*8, Bs + (size_t)idx*8);
    }
    __syncthreads();
    bf16x8 af[4], bf[4];
    #pragma unroll
    for (int mt = 0; mt < 4; mt++)
      af[mt] = *(const bf16x8*)(As + (wr*64 + mt*16 + l15)*32 + q4*8);
    #pragma unroll
    for (int nt = 0; nt < 4; nt++)
      bf[nt] = *(const bf16x8*)(Bs + (wc*64 + nt*16 + l15)*32 + q4*8);
    #pragma unroll
    for (int mt = 0; mt < 4; mt++)
      #pragma unroll
      for (int nt = 0; nt < 4; nt++)
        acc[mt][nt] = __builtin_amdgcn_mfma_f32_16x16x32_bf16(af[mt], bf[nt], acc[mt][nt], 0, 0, 0);
    __syncthreads();
  }
  const int bb = row0 >> 12;            // batch
  const int tile0 = (row0 >> 6) & 63;   // first 64-token tile of this block
  const int col0 = yb*128 + wc*64;      // global channel base for this wave
  u8* Ls = (u8*)SMEM;                   // 16KB staging

  if (mat == 0){
    // stage Q fp8 tile [128 rows][128 cols] into LDS, then coalesced stores
    #pragma unroll
    for (int nt = 0; nt < 4; nt++){
      int n = col0 + nt*16 + l15;
      float bv = qbias[n];
      int cloc = wc*64 + nt*16 + l15;
      #pragma unroll
      for (int mt = 0; mt < 4; mt++){
        int rloc = wr*64 + mt*16 + q4*4;
        #pragma unroll
        for (int r = 0; r < 4; r++)
          Ls[(rloc + r)*128 + cloc] = f2e4(acc[mt][nt][r] + bv);
      }
    }
    __syncthreads();
    #pragma unroll
    for (int i = 0; i < 4; i++){
      int ci = i*256 + t;                    // 16B chunk 0..1023
      u8* dst = qo + (size_t)(row0 + (ci >> 3))*512 + yb*128 + (ci & 7)*16;
      *(float4*)dst = *(const float4*)(Ls + (size_t)ci*16);
    }
  } else if (mat == 1){
    // stage into LDS in exact global within-tile layout
    #pragma unroll
    for (int nt = 0; nt < 4; nt++){
      int n = col0 + nt*16 + l15;
      float bv = kbias[n];
      int ksl = wc*2 + (nt >> 1);            // block-local ks (0..3)
      int c3  = ((nt & 1)*2 + (l15 >> 3));   // ch>>3 within 32-ch group
      #pragma unroll
      for (int mt = 0; mt < 4; mt++){
        #pragma unroll
        for (int r = 0; r < 4; r++){
          int kr = mt*16 + q4*4 + r;
          int chunk = c3 ^ ((kr >> 2) & 3);
          Ls[(wr*4 + ksl)*2048 + kr*32 + chunk*8 + (l15 & 7)] = f2e4(acc[mt][nt][r] + bv);
        }
      }
    }
    __syncthreads();
    #pragma unroll
    for (int i = 0; i < 4; i++){
      int ci = i*256 + t;                    // 16B chunk 0..1023
      int ri = ci >> 7, t2 = ri >> 2, ksl2 = ri & 3;
      u8* dst = ko + ((size_t)(bb*64 + tile0 + t2))*32768
                   + (size_t)(yb*4 + ksl2)*2048 + (size_t)(ci & 127)*16;
      *(float4*)dst = *(const float4*)(Ls + (size_t)ci*16);
    }
  } else {
    #pragma unroll
    for (int nt = 0; nt < 4; nt++){
      int n = col0 + nt*16 + l15;
      float bv = vbias[n];
      int nl = n & 127;
      #pragma unroll
      for (int mt = 0; mt < 4; mt++){
        int kv = mt*16 + q4*4;
        u32 pk = (u32)f2e4(acc[mt][nt][0] + bv)
               | ((u32)f2e4(acc[mt][nt][1] + bv) << 8)
               | ((u32)f2e4(acc[mt][nt][2] + bv) << 16)
               | ((u32)f2e4(acc[mt][nt][3] + bv) << 24);
        int phys = (kv >> 3) ^ (n & 7);
        *(u32*)(Ls + wr*8192 + nl*64 + phys*8 + (kv & 4)) = pk;
      }
    }
    __syncthreads();
    #pragma unroll
    for (int i = 0; i < 4; i++){
      int ci = i*256 + t;                    // 16B chunk 0..1023
      int t2 = ci >> 9;
      u8* dst = vo + ((size_t)(bb*64 + tile0 + t2))*32768
                   + (size_t)yb*8192 + (size_t)(ci & 511)*16;
      *(float4*)dst = *(const float4*)(Ls + (size_t)ci*16);
    }
  }
}

// ----------- out-proj gemm + bias + residual + transpose (fp32 out) --------
__global__ __launch_bounds__(256, 2) void out_gemm(const u16* __restrict__ A,
                                                   const u16* __restrict__ Bw,
                                                   const float* __restrict__ bias,
                                                   float* __restrict__ out,
                                                   const float* __restrict__ resid){
  __shared__ __align__(16) u16 As[128*32];
  __shared__ __align__(16) u16 Bs[128*32];
  const int t = threadIdx.x;
  const int w = t >> 6, ln = t & 63;
  const int wr = w >> 1, wc = w & 1;
  const int q4 = ln >> 4, l15 = ln & 15;
  const u16* Ab = A  + (size_t)blockIdx.x * 128 * 512;
  const u16* Bb = Bw + (size_t)blockIdx.y * 128 * 512;
  f32x4 acc[4][4];
  #pragma unroll
  for (int i = 0; i < 4; i++)
    #pragma unroll
    for (int j = 0; j < 4; j++){
      acc[i][j][0]=0.f; acc[i][j][1]=0.f; acc[i][j][2]=0.f; acc[i][j][3]=0.f;
    }
  for (int kt = 0; kt < 16; ++kt){
    #pragma unroll
    for (int i = 0; i < 2; i++){
      int idx = i*256 + t;
      gload16(Ab + (size_t)(idx>>2)*512 + kt*32 + (idx&3)*8, As + (size_t)idx*8);
      gload16(Bb + (size_t)(idx>>2)*512 + kt*32 + (idx&3)*8, Bs + (size_t)idx*8);
    }
    __syncthreads();
    bf16x8 af[4], bf[4];
    #pragma unroll
    for (int mt = 0; mt < 4; mt++)
      af[mt] = *(const bf16x8*)(As + (wr*64 + mt*16 + l15)*32 + q4*8);
    #pragma unroll
    for (int nt = 0; nt < 4; nt++)
      bf[nt] = *(const bf16x8*)(Bs + (wc*64 + nt*16 + l15)*32 + q4*8);
    #pragma unroll
    for (int mt = 0; mt < 4; mt++)
      #pragma unroll
      for (int nt = 0; nt < 4; nt++)
        acc[mt][nt] = __builtin_amdgcn_mfma_f32_16x16x32_bf16(af[mt], bf[nt], acc[mt][nt], 0, 0, 0);
    __syncthreads();
  }
  const int row0 = blockIdx.x*128 + wr*64;
  const int col0 = blockIdx.y*128 + wc*64;
  #pragma unroll
  for (int nt = 0; nt < 4; nt++){
    int n = col0 + nt*16 + l15;
    float bv = bias[n];
    #pragma unroll
    for (int mt = 0; mt < 4; mt++){
      int m0 = row0 + mt*16 + q4*4;
      int bb = m0 >> 12, tok = m0 & 4095;
      size_t base = (((size_t)(bb*512 + n)) << 12) + tok;
      float4 xr = *(const float4*)(resid + base);
      float4 ov;
      ov.x = acc[mt][nt][0] + bv + xr.x;
      ov.y = acc[mt][nt][1] + bv + xr.y;
      ov.z = acc[mt][nt][2] + bv + xr.z;
      ov.w = acc[mt][nt][3] + bv + xr.w;
      *(float4*)(out + base) = ov;
    }
  }
}

// ---------------------------- flash attention ------------------------------
// q fp8 [b,tok,512]; kt fp8 tiled [b][64][ks16][kr64][ch32] (swizzled);
// vt fp8 tiled [b][64][c512][kv64] (swizzled); out O bf16 [b,tok,512].
// BM=32, BN=64, 256 threads (4 waves), 2 blocks/CU, 64 iterations.
// All-fp8 MFMA. V loads issued BEFORE K-DMA (R10: PV wait = vmcnt(8), DMA
// stays in flight through PV). S computed SWAPPED: mfma(K, Q) — A/B fragment
// layouts are symmetric so the SAME registers serve with roles swapped; the
// output transposes so each lane holds 4 CONSECUTIVE kv of one q-row
// (q = rt*16+l15, kv = chh*32 [+16] + q4*4+r; verified on HW R5/R11).
// Softmax packs P as 2x ds_write_b32 via v_cvt_pk_fp8_f32; l-row is a scalar
// with a 2-shuffle epilogue reduce. R11 = best measured (137 µs).
// CLOSED doors (measured): MX mfma_scale S (R4 spill -25%; R12 no-spill -6%,
// operand marshalling), s_setprio (-5%, R8), LDS-free K (-54%, R6), wave
// specialization (-25%, R5), 8-wave (0, R3), fused lagged-PV (0, R2).
__global__ __launch_bounds__(256, 2) void attn_fwd(const u8* __restrict__ q,
                                                   const u8* __restrict__ kt,
                                                   const u8* __restrict__ vt,
                                                   u16* __restrict__ outO){
  __shared__ __align__(16) u8 Kb[2][32768];    // 2 x 32KB fp8 K tiles
  __shared__ __align__(16) u8 Pb[32*72];       // P fp8 [qrow32][kv64 +8 pad]
  __shared__ __align__(16) float lL[64];       // [chh][row32]

  const int t = threadIdx.x, w = t >> 6, ln = t & 63;
  const int q4 = ln >> 4, l15 = ln & 15;
  const int rt = w >> 1, chh = w & 1;          // S role: row-tile, col-half
  const int b = blockIdx.y, q0 = blockIdx.x * 32;
  const u8* kbase = kt + ((size_t)b << 21);
  const u8* vbase = vt + ((size_t)b << 21);

  // Q fragments fp8: rows q0 + rt*16 + l15, all 512 ch (32 VGPR)
  long qf[16];
  {
    const u8* qr = q + (size_t)((b<<12) + q0 + rt*16 + l15) * 512;
    #pragma unroll
    for (int ks = 0; ks < 16; ks++) qf[ks] = *(const long*)(qr + ks*32 + q4*8);
  }
  f32x4 oacc[2][8];
  #pragma unroll
  for (int i = 0; i < 2; i++)
    #pragma unroll
    for (int j = 0; j < 8; j++){
      oacc[i][j][0]=0.f; oacc[i][j][1]=0.f; oacc[i][j][2]=0.f; oacc[i][j][3]=0.f;
    }
  float lrow = 0.f;

  // K-tile read offsets (two col-tiles per wave), swizzle baked in layout
  const int kr0 = chh*32 + l15,  kr1 = chh*32 + 16 + l15;
  const int ko0 = kr0*32 + ((q4 ^ ((kr0 >> 2) & 3)) << 3);
  const int ko1 = kr1*32 + ((q4 ^ ((kr1 >> 2) & 3)) << 3);

  // prologue: DMA K tile 0 into Kb[0] (2048 x 16B chunks, 8 per thread)
  #pragma unroll
  for (int i = 0; i < 8; i++){
    int ci = i*256 + t;
    gload16(kbase + (size_t)ci*16, &Kb[0][ci*16]);
  }
  __syncthreads();

  #pragma unroll 1
  for (int j = 0; j < 64; ++j){
    // 1. V fragment loads from L2 EARLY (issued FIRST so the PV wait is
    //    vmcnt(8), leaving the K-DMA in flight through PV)
    long vf0[8], vf1[8];
    {
      const u8* vtile = vbase + ((size_t)j << 15);
      #pragma unroll
      for (int ct = 0; ct < 8; ct++){
        int ch = 128*w + ct*16 + l15;
        int swz = ch & 7;
        const u8* vr = vtile + (size_t)ch*64;
        vf0[ct] = *(const long*)(vr + ((q4 ^ swz) << 3));
        vf1[ct] = *(const long*)(vr + (((4 + q4) ^ swz) << 3));
      }
    }
    // 2. issue DMA for K tile j+1 (other buffer; drains at end-of-iter sync)
    {
      const u8* kn = kbase + ((size_t)((j + 1) & 63) << 15);
      u8* kd = Kb[(j + 1) & 1];
      #pragma unroll
      for (int i = 0; i < 8; i++){
        int ci = i*256 + t;
        gload16(kn + (size_t)ci*16, kd + ci*16);
      }
    }
    // 3. S^T = K Q^T (fp8, swapped operands): 4 independent chains.
    //    Lane (q4,l15) accumulates S[q=rt*16+l15][kv=chh*32(+16)+q4*4+r].
    const u8* Kp = Kb[j & 1];
    f32x4 sA0, sA1, sB0, sB1;
    sA0[0]=0.f;sA0[1]=0.f;sA0[2]=0.f;sA0[3]=0.f;
    sA1[0]=0.f;sA1[1]=0.f;sA1[2]=0.f;sA1[3]=0.f;
    sB0[0]=0.f;sB0[1]=0.f;sB0[2]=0.f;sB0[3]=0.f;
    sB1[0]=0.f;sB1[1]=0.f;sB1[2]=0.f;sB1[3]=0.f;
    #pragma unroll
    for (int k2 = 0; k2 < 8; k2++){
      const u8* e0 = Kp + (2*k2)*2048;
      const u8* e1 = Kp + (2*k2 + 1)*2048;
      long ka0 = *(const long*)(e0 + ko0);
      long kb0 = *(const long*)(e0 + ko1);
      long ka1 = *(const long*)(e1 + ko0);
      long kb1 = *(const long*)(e1 + ko1);
      sA0 = __builtin_amdgcn_mfma_f32_16x16x32_fp8_fp8(ka0, qf[2*k2],   sA0, 0, 0, 0);
      sB0 = __builtin_amdgcn_mfma_f32_16x16x32_fp8_fp8(kb0, qf[2*k2],   sB0, 0, 0, 0);
      sA1 = __builtin_amdgcn_mfma_f32_16x16x32_fp8_fp8(ka1, qf[2*k2+1], sA1, 0, 0, 0);
      sB1 = __builtin_amdgcn_mfma_f32_16x16x32_fp8_fp8(kb1, qf[2*k2+1], sB1, 0, 0, 0);
    }
    // 4. max-free softmax -> P fp8 in LDS (packed u32 writes)
    {
      float a0 = __expf((sA0[0] + sA1[0]) * SCALE_Q);
      float a1 = __expf((sA0[1] + sA1[1]) * SCALE_Q);
      float a2 = __expf((sA0[2] + sA1[2]) * SCALE_Q);
      float a3 = __expf((sA0[3] + sA1[3]) * SCALE_Q);
      float b0 = __expf((sB0[0] + sB1[0]) * SCALE_Q);
      float b1 = __expf((sB0[1] + sB1[1]) * SCALE_Q);
      float b2 = __expf((sB0[2] + sB1[2]) * SCALE_Q);
      float b3 = __expf((sB0[3] + sB1[3]) * SCALE_Q);
      lrow += ((a0 + a1) + (a2 + a3)) + ((b0 + b1) + (b2 + b3));
      u8* Pw = Pb + (rt*16 + l15)*72 + chh*32 + q4*4;
      *(u32*)(Pw)      = pk4e4(a0, a1, a2, a3);
      *(u32*)(Pw + 16) = pk4e4(b0, b1, b2, b3);
    }
    BAR();                                   // P visible; DMA + vf in flight
    // 5. PV (fp8): O += P V ; wave owns col strip [128w, 128w+128)
    {
      long pf00 = *(const long*)(Pb + l15*72 + q4*8);
      long pf01 = *(const long*)(Pb + l15*72 + 32 + q4*8);
      long pf10 = *(const long*)(Pb + (16 + l15)*72 + q4*8);
      long pf11 = *(const long*)(Pb + (16 + l15)*72 + 32 + q4*8);
      #pragma unroll
      for (int ct = 0; ct < 8; ct++){
        f32x4 a0 = oacc[0][ct], a1 = oacc[1][ct];
        a0 = __builtin_amdgcn_mfma_f32_16x16x32_fp8_fp8(pf00, vf0[ct], a0, 0, 0, 0);
        a1 = __builtin_amdgcn_mfma_f32_16x16x32_fp8_fp8(pf10, vf0[ct], a1, 0, 0, 0);
        a0 = __builtin_amdgcn_mfma_f32_16x16x32_fp8_fp8(pf01, vf1[ct], a0, 0, 0, 0);
        a1 = __builtin_amdgcn_mfma_f32_16x16x32_fp8_fp8(pf11, vf1[ct], a1, 0, 0, 0);
        oacc[0][ct] = a0; oacc[1][ct] = a1;
      }
    }
    __syncthreads();                         // drains DMA(j+1) before S(j+1)
  }

  // ---- epilogue: reduce l across q4 groups + the two col-half waves ----
  {
    float v = lrow;
    v += __shfl_xor(v, 16);
    v += __shfl_xor(v, 32);
    if (ln < 16) lL[chh*32 + rt*16 + ln] = v;
  }
  __syncthreads();
  #pragma unroll
  for (int rr = 0; rr < 2; rr++){
    #pragma unroll
    for (int r = 0; r < 4; r++){
      int row = rr*16 + q4*4 + r;
      float inv = 1.f / (lL[row] + lL[32 + row]);
      u16* op = outO + ((size_t)b << 21) + (size_t)(q0 + row)*512 + 128*w + l15;
      #pragma unroll
      for (int ct = 0; ct < 8; ct++)
        op[ct*16] = f2b(oacc[rr][ct][r] * inv);
    }
  }
}

extern "C" void kernel_launch(void* const* d_in, const int* in_sizes, int n_in,
                              void* d_out, int out_size, void* d_ws, size_t ws_size,
                              hipStream_t stream){
  const float* x     = (const float*)d_in[0];
  const float* gamma = (const float*)d_in[1];
  const float* beta  = (const float*)d_in[2];
  const float* wq_w  = (const float*)d_in[3];
  const float* wq_b  = (const float*)d_in[4];
  const float* wk_w  = (const float*)d_in[5];
  const float* wk_b  = (const float*)d_in[6];
  const float* wv_w  = (const float*)d_in[7];
  const float* wv_b  = (const float*)d_in[8];
  const float* out_w = (const float*)d_in[9];
  const float* out_b = (const float*)d_in[10];

  char* ws = (char*)d_ws;
  float* stats = (float*)ws;                                   // 1 KB
  u16* tbuf = (u16*)(ws + 4096);                               // 16 MB (t, then O)
  size_t off = 4096 + (size_t)16*1024*1024;
  u16* Wcat = (u16*)(ws + off); off += (size_t)4*512*512*2;    // 2 MB
  u8*  qb   = (u8*)(ws + off);  off += (size_t)16*1024*1024;   // Q fp8
  u8*  ktb  = (u8*)(ws + off);  off += (size_t)16*1024*1024;   // K fp8 tiled
  u8*  vtb  = (u8*)(ws + off);  off += (size_t)16*1024*1024;   // V fp8 tiled

  gn_stats<<<128, 256, 0, stream>>>(x, stats);
  gn_apply_T<<<dim3(128, 16, 4), 256, 0, stream>>>(x, stats, gamma, beta, tbuf);
  w2bf<<<1024, 256, 0, stream>>>(wq_w, wk_w, wv_w, out_w, Wcat);
  u16* Wo = Wcat + 3*512*512;
  qkv_gemm<<<dim3(128, 12), 256, 0, stream>>>(tbuf, Wcat, wq_b, wk_b, wv_b,
                                              qb, ktb, vtb);
  attn_fwd<<<dim3(128, 4), 256, 0, stream>>>(qb, ktb, vtb, tbuf);
  out_gemm<<<dim3(128, 4), 256, 0, stream>>>(tbuf, Wo, out_b, (float*)d_out, x);
}

// Round 14
// 317.004 us; speedup vs baseline: 1.0375x; 1.0243x over previous
//
#include <hip/hip_runtime.h>
#include <hip/hip_fp8.h>

typedef unsigned short u16;
typedef unsigned char u8;
typedef unsigned int u32;
typedef short bf16x8 __attribute__((ext_vector_type(8)));
typedef float f32x4 __attribute__((ext_vector_type(4)));
typedef u16 u16x4 __attribute__((ext_vector_type(4)));

#define SCALE_Q 0.044194173824159216f   // 1/sqrt(512)

// barrier WITHOUT vmcnt drain (lgkm only): in-flight global/DMA ops survive.
#define BAR() asm volatile("s_waitcnt lgkmcnt(0)\n\ts_barrier" ::: "memory")

__device__ __forceinline__ u16 f2b(float f){   // fp32 -> bf16 RNE
  unsigned u = __float_as_uint(f);
  u += 0x7fffu + ((u >> 16) & 1u);
  return (u16)(u >> 16);
}

__device__ __forceinline__ u8 f2e4(float f){   // fp32 -> fp8 e4m3 (OCP)
  return __hip_fp8_e4m3(f).__x;
}

__device__ __forceinline__ u32 pk4e4(float e0, float e1, float e2, float e3){
#if defined(__has_builtin) && __has_builtin(__builtin_amdgcn_cvt_pk_fp8_f32)
  int pk = __builtin_amdgcn_cvt_pk_fp8_f32(e0, e1, 0, false);
  pk = __builtin_amdgcn_cvt_pk_fp8_f32(e2, e3, pk, true);
  return (u32)pk;
#else
  return (u32)f2e4(e0) | ((u32)f2e4(e1) << 8)
       | ((u32)f2e4(e2) << 16) | ((u32)f2e4(e3) << 24);
#endif
}

__device__ __forceinline__ void gload16(const void* g, void* l){
  __builtin_amdgcn_global_load_lds(
      (const __attribute__((address_space(1))) void*)g,
      (__attribute__((address_space(3))) void*)l, 16, 0, 0);
}

// ---------------- GroupNorm stats: one block per (b, group) ----------------
__global__ __launch_bounds__(256) void gn_stats(const float* __restrict__ x,
                                                float* __restrict__ stats){
  int bg = blockIdx.x;
  const float4* p4 = (const float4*)(x + (size_t)bg * 65536);
  float s = 0.f, ss = 0.f;
  for (int i = threadIdx.x; i < 16384; i += 256){
    float4 v = p4[i];
    s  += v.x + v.y + v.z + v.w;
    ss += v.x*v.x + v.y*v.y + v.z*v.z + v.w*v.w;
  }
  for (int off = 32; off; off >>= 1){
    s  += __shfl_down(s, off);
    ss += __shfl_down(ss, off);
  }
  __shared__ float as_[4], bs_[4];
  int wid = threadIdx.x >> 6, lid = threadIdx.x & 63;
  if (lid == 0){ as_[wid] = s; bs_[wid] = ss; }
  __syncthreads();
  if (threadIdx.x == 0){
    float S = as_[0]+as_[1]+as_[2]+as_[3], SS = bs_[0]+bs_[1]+bs_[2]+bs_[3];
    float mean = S * (1.f/65536.f);
    float var  = SS * (1.f/65536.f) - mean*mean;
    stats[2*bg]   = mean;
    stats[2*bg+1] = rsqrtf(var + 1e-6f);
  }
}

// ------- normalize + affine + transpose [b,c,N] -> t[b,N,c] (bf16) ---------
__global__ __launch_bounds__(256) void gn_apply_T(const float* __restrict__ x,
                                                  const float* __restrict__ stats,
                                                  const float* __restrict__ gamma,
                                                  const float* __restrict__ beta,
                                                  u16* __restrict__ t){
  __shared__ float tile[32][33];
  int nb = blockIdx.x, cb = blockIdx.y, b = blockIdx.z;
  int tx = threadIdx.x & 31, ty = threadIdx.x >> 5;
  int n0 = nb * 32, c0 = cb * 32;
  #pragma unroll
  for (int i = 0; i < 4; i++){
    int ch = c0 + ty + i*8;
    float mean = stats[2*((b<<5) + (ch>>4))];
    float rstd = stats[2*((b<<5) + (ch>>4)) + 1];
    float v = x[(((size_t)b*512 + ch) << 12) + n0 + tx];
    tile[ty + i*8][tx] = (v - mean) * rstd * gamma[ch] + beta[ch];
  }
  __syncthreads();
  #pragma unroll
  for (int i = 0; i < 4; i++){
    int n = n0 + ty + i*8;
    int ch = c0 + tx;
    t[((size_t)((b<<12) + n))*512 + ch] = f2b(tile[tx][ty + i*8]);
  }
}

// ---------------- fp32 -> bf16 weight conversion (4 matrices) --------------
__global__ __launch_bounds__(256) void w2bf(const float* __restrict__ a,
                                            const float* __restrict__ b,
                                            const float* __restrict__ c,
                                            const float* __restrict__ d,
                                            u16* __restrict__ o){
  int idx = blockIdx.x * 256 + threadIdx.x;
  int which = idx >> 16;
  const float4* src = (const float4*)(which == 0 ? a : which == 1 ? b : which == 2 ? c : d);
  float4 v = src[idx & 65535];
  u16x4 pk;
  pk.x = f2b(v.x); pk.y = f2b(v.y); pk.z = f2b(v.z); pk.w = f2b(v.w);
  *(u16x4*)(o + (size_t)idx*4) = pk;
}

// ------------- fused QKV gemm: grid (128, 12); y>>2 selects matrix ---------
// mat 0 -> Q fp8 e4m3 [b,tok,c] (unscaled), staged through LDS (coalesced)
// mat 1 -> K fp8 tiled [b][tile64][ks16][kr64][ch32], chunk swz = q4^((kr>>2)&3)
// mat 2 -> V fp8 tiled [b][tile64][c512][kv64], chunk swz = chunk^(n&7)
// All epilogues staged through LDS -> coalesced dwordx4 global stores.
// launch_bounds (256,4): 4 resident blocks/CU (no spill; verified R10).
__global__ __launch_bounds__(256, 4) void qkv_gemm(const u16* __restrict__ A,
                                                   const u16* __restrict__ Wcat,
                                                   const float* __restrict__ qbias,
                                                   const float* __restrict__ kbias,
                                                   const float* __restrict__ vbias,
                                                   u8* __restrict__ qo,
                                                   u8* __restrict__ ko,
                                                   u8* __restrict__ vo){
  __shared__ __align__(16) u16 SMEM[8192];     // As | Bs, reused as 16KB stage
  u16* As = SMEM;
  u16* Bs = SMEM + 4096;
  const int t = threadIdx.x;
  const int w = t >> 6, ln = t & 63;
  const int wr = w >> 1, wc = w & 1;
  const int q4 = ln >> 4, l15 = ln & 15;
  const int y = blockIdx.y;
  const int mat = y >> 2, yb = y & 3;
  const int row0 = blockIdx.x * 128;
  const u16* Ab = A    + (size_t)row0 * 512;
  const u16* Bb = Wcat + (size_t)y * 128 * 512;
  f32x4 acc[4][4];
  #pragma unroll
  for (int i = 0; i < 4; i++)
    #pragma unroll
    for (int j = 0; j < 4; j++){
      acc[i][j][0]=0.f; acc[i][j][1]=0.f; acc[i][j][2]=0.f; acc[i][j][3]=0.f;
    }
  for (int kt = 0; kt < 16; ++kt){
    #pragma unroll
    for (int i = 0; i < 2; i++){
      int idx = i*256 + t;
      gload16(Ab + (size_t)(idx>>2)*512 + kt*32 + (idx&3)*8, As + (size_t)idx*8);
      gload16(Bb + (size_t)(idx>>2)*512 + kt*32 + (idx&3)*8, Bs + (size_t)idx*8);
    }
    __syncthreads();
    bf16x8 af[4], bf[4];
    #pragma unroll
    for (int mt = 0; mt < 4; mt++)
      af[mt] = *(const bf16x8*)(As + (wr*64 + mt*16 + l15)*32 + q4*8);
    #pragma unroll
    for (int nt = 0; nt < 4; nt++)
      bf[nt] = *(const bf16x8*)(Bs + (wc*64 + nt*16 + l15)*32 + q4*8);
    #pragma unroll
    for (int mt = 0; mt < 4; mt++)
      #pragma unroll
      for (int nt = 0; nt < 4; nt++)
        acc[mt][nt] = __builtin_amdgcn_mfma_f32_16x16x32_bf16(af[mt], bf[nt], acc[mt][nt], 0, 0, 0);
    __syncthreads();
  }
  const int bb = row0 >> 12;            // batch
  const int tile0 = (row0 >> 6) & 63;   // first 64-token tile of this block
  const int col0 = yb*128 + wc*64;      // global channel base for this wave
  u8* Ls = (u8*)SMEM;                   // 16KB staging

  if (mat == 0){
    // stage Q fp8 tile [128 rows][128 cols] into LDS, then coalesced stores
    #pragma unroll
    for (int nt = 0; nt < 4; nt++){
      int n = col0 + nt*16 + l15;
      float bv = qbias[n];
      int cloc = wc*64 + nt*16 + l15;
      #pragma unroll
      for (int mt = 0; mt < 4; mt++){
        int rloc = wr*64 + mt*16 + q4*4;
        #pragma unroll
        for (int r = 0; r < 4; r++)
          Ls[(rloc + r)*128 + cloc] = f2e4(acc[mt][nt][r] + bv);
      }
    }
    __syncthreads();
    #pragma unroll
    for (int i = 0; i < 4; i++){
      int ci = i*256 + t;                    // 16B chunk 0..1023
      u8* dst = qo + (size_t)(row0 + (ci >> 3))*512 + yb*128 + (ci & 7)*16;
      *(float4*)dst = *(const float4*)(Ls + (size_t)ci*16);
    }
  } else if (mat == 1){
    // stage into LDS in exact global within-tile layout
    #pragma unroll
    for (int nt = 0; nt < 4; nt++){
      int n = col0 + nt*16 + l15;
      float bv = kbias[n];
      int ksl = wc*2 + (nt >> 1);            // block-local ks (0..3)
      int c3  = ((nt & 1)*2 + (l15 >> 3));   // ch>>3 within 32-ch group
      #pragma unroll
      for (int mt = 0; mt < 4; mt++){
        #pragma unroll
        for (int r = 0; r < 4; r++){
          int kr = mt*16 + q4*4 + r;
          int chunk = c3 ^ ((kr >> 2) & 3);
          Ls[(wr*4 + ksl)*2048 + kr*32 + chunk*8 + (l15 & 7)] = f2e4(acc[mt][nt][r] + bv);
        }
      }
    }
    __syncthreads();
    #pragma unroll
    for (int i = 0; i < 4; i++){
      int ci = i*256 + t;                    // 16B chunk 0..1023
      int ri = ci >> 7, t2 = ri >> 2, ksl2 = ri & 3;
      u8* dst = ko + ((size_t)(bb*64 + tile0 + t2))*32768
                   + (size_t)(yb*4 + ksl2)*2048 + (size_t)(ci & 127)*16;
      *(float4*)dst = *(const float4*)(Ls + (size_t)ci*16);
    }
  } else {
    #pragma unroll
    for (int nt = 0; nt < 4; nt++){
      int n = col0 + nt*16 + l15;
      float bv = vbias[n];
      int nl = n & 127;
      #pragma unroll
      for (int mt = 0; mt < 4; mt++){
        int kv = mt*16 + q4*4;
        u32 pk = (u32)f2e4(acc[mt][nt][0] + bv)
               | ((u32)f2e4(acc[mt][nt][1] + bv) << 8)
               | ((u32)f2e4(acc[mt][nt][2] + bv) << 16)
               | ((u32)f2e4(acc[mt][nt][3] + bv) << 24);
        int phys = (kv >> 3) ^ (n & 7);
        *(u32*)(Ls + wr*8192 + nl*64 + phys*8 + (kv & 4)) = pk;
      }
    }
    __syncthreads();
    #pragma unroll
    for (int i = 0; i < 4; i++){
      int ci = i*256 + t;                    // 16B chunk 0..1023
      int t2 = ci >> 9;
      u8* dst = vo + ((size_t)(bb*64 + tile0 + t2))*32768
                   + (size_t)yb*8192 + (size_t)(ci & 511)*16;
      *(float4*)dst = *(const float4*)(Ls + (size_t)ci*16);
    }
  }
}

// ----------- out-proj gemm + bias + residual + transpose (fp32 out) --------
__global__ __launch_bounds__(256, 2) void out_gemm(const u16* __restrict__ A,
                                                   const u16* __restrict__ Bw,
                                                   const float* __restrict__ bias,
                                                   float* __restrict__ out,
                                                   const float* __restrict__ resid){
  __shared__ __align__(16) u16 As[128*32];
  __shared__ __align__(16) u16 Bs[128*32];
  const int t = threadIdx.x;
  const int w = t >> 6, ln = t & 63;
  const int wr = w >> 1, wc = w & 1;
  const int q4 = ln >> 4, l15 = ln & 15;
  const u16* Ab = A  + (size_t)blockIdx.x * 128 * 512;
  const u16* Bb = Bw + (size_t)blockIdx.y * 128 * 512;
  f32x4 acc[4][4];
  #pragma unroll
  for (int i = 0; i < 4; i++)
    #pragma unroll
    for (int j = 0; j < 4; j++){
      acc[i][j][0]=0.f; acc[i][j][1]=0.f; acc[i][j][2]=0.f; acc[i][j][3]=0.f;
    }
  for (int kt = 0; kt < 16; ++kt){
    #pragma unroll
    for (int i = 0; i < 2; i++){
      int idx = i*256 + t;
      gload16(Ab + (size_t)(idx>>2)*512 + kt*32 + (idx&3)*8, As + (size_t)idx*8);
      gload16(Bb + (size_t)(idx>>2)*512 + kt*32 + (idx&3)*8, Bs + (size_t)idx*8);
    }
    __syncthreads();
    bf16x8 af[4], bf[4];
    #pragma unroll
    for (int mt = 0; mt < 4; mt++)
      af[mt] = *(const bf16x8*)(As + (wr*64 + mt*16 + l15)*32 + q4*8);
    #pragma unroll
    for (int nt = 0; nt < 4; nt++)
      bf[nt] = *(const bf16x8*)(Bs + (wc*64 + nt*16 + l15)*32 + q4*8);
    #pragma unroll
    for (int mt = 0; mt < 4; mt++)
      #pragma unroll
      for (int nt = 0; nt < 4; nt++)
        acc[mt][nt] = __builtin_amdgcn_mfma_f32_16x16x32_bf16(af[mt], bf[nt], acc[mt][nt], 0, 0, 0);
    __syncthreads();
  }
  const int row0 = blockIdx.x*128 + wr*64;
  const int col0 = blockIdx.y*128 + wc*64;
  #pragma unroll
  for (int nt = 0; nt < 4; nt++){
    int n = col0 + nt*16 + l15;
    float bv = bias[n];
    #pragma unroll
    for (int mt = 0; mt < 4; mt++){
      int m0 = row0 + mt*16 + q4*4;
      int bb = m0 >> 12, tok = m0 & 4095;
      size_t base = (((size_t)(bb*512 + n)) << 12) + tok;
      float4 xr = *(const float4*)(resid + base);
      float4 ov;
      ov.x = acc[mt][nt][0] + bv + xr.x;
      ov.y = acc[mt][nt][1] + bv + xr.y;
      ov.z = acc[mt][nt][2] + bv + xr.z;
      ov.w = acc[mt][nt][3] + bv + xr.w;
      *(float4*)(out + base) = ov;
    }
  }
}

// ---------------------------- flash attention ------------------------------
// q fp8 [b,tok,512]; kt fp8 tiled [b][64][ks16][kr64][ch32] (swizzled);
// vt fp8 tiled [b][64][c512][kv64] (swizzled); out O bf16 [b,tok,512].
// BM=32, BN=64, 256 threads (4 waves), 2 blocks/CU, 64 iterations.
// All-fp8 MFMA. V loads issued BEFORE K-DMA (R10). S computed SWAPPED:
// mfma(K, Q) so each lane holds 4 consecutive kv of one q-row (R11); P packed
// as 2x ds_write_b32 via v_cvt_pk_fp8_f32; scalar l-row.
// R14: XCD-partitioned block decode. Default linear id = x + 128*b maps XCD
// (= id mod 8) by x mod 8 -> every XCD touches all 4 batches (16 MB K/V >
// 4 MB L2 -> evictions, FETCH 70 MB vs 48 unique). Remap (bijective on 512):
// b = (id>>1)&3, x = (id>>3)*2 + (id&1)  => each batch owns 2 XCDs; per-XCD
// K/V working set = 4 MB = L2 size. Work permutation only; numerics identical.
// CLOSED doors (measured): MX mfma_scale S (R4 -25% spill; R12 -6% no-spill),
// s_setprio (-5%, R8), LDS-free K (-54%, R6), specialization (-25%, R5),
// 8-wave (0, R3), fused lagged-PV (0, R2).
__global__ __launch_bounds__(256, 2) void attn_fwd(const u8* __restrict__ q,
                                                   const u8* __restrict__ kt,
                                                   const u8* __restrict__ vt,
                                                   u16* __restrict__ outO){
  __shared__ __align__(16) u8 Kb[2][32768];    // 2 x 32KB fp8 K tiles
  __shared__ __align__(16) u8 Pb[32*72];       // P fp8 [qrow32][kv64 +8 pad]
  __shared__ __align__(16) float lL[64];       // [chh][row32]

  const int t = threadIdx.x, w = t >> 6, ln = t & 63;
  const int q4 = ln >> 4, l15 = ln & 15;
  const int rt = w >> 1, chh = w & 1;          // S role: row-tile, col-half
  // XCD-partitioned decode: batch pinned to an XCD pair (see header comment)
  const int id = blockIdx.x + (blockIdx.y << 7);
  const int b  = (id >> 1) & 3;
  const int q0 = (((id >> 3) << 1) | (id & 1)) * 32;
  const u8* kbase = kt + ((size_t)b << 21);
  const u8* vbase = vt + ((size_t)b << 21);

  // Q fragments fp8: rows q0 + rt*16 + l15, all 512 ch (32 VGPR)
  long qf[16];
  {
    const u8* qr = q + (size_t)((b<<12) + q0 + rt*16 + l15) * 512;
    #pragma unroll
    for (int ks = 0; ks < 16; ks++) qf[ks] = *(const long*)(qr + ks*32 + q4*8);
  }
  f32x4 oacc[2][8];
  #pragma unroll
  for (int i = 0; i < 2; i++)
    #pragma unroll
    for (int j = 0; j < 8; j++){
      oacc[i][j][0]=0.f; oacc[i][j][1]=0.f; oacc[i][j][2]=0.f; oacc[i][j][3]=0.f;
    }
  float lrow = 0.f;

  // K-tile read offsets (two col-tiles per wave), swizzle baked in layout
  const int kr0 = chh*32 + l15,  kr1 = chh*32 + 16 + l15;
  const int ko0 = kr0*32 + ((q4 ^ ((kr0 >> 2) & 3)) << 3);
  const int ko1 = kr1*32 + ((q4 ^ ((kr1 >> 2) & 3)) << 3);

  // prologue: DMA K tile 0 into Kb[0] (2048 x 16B chunks, 8 per thread)
  #pragma unroll
  for (int i = 0; i < 8; i++){
    int ci = i*256 + t;
    gload16(kbase + (size_t)ci*16, &Kb[0][ci*16]);
  }
  __syncthreads();

  #pragma unroll 1
  for (int j = 0; j < 64; ++j){
    // 1. V fragment loads from L2 EARLY (issued FIRST so the PV wait is
    //    vmcnt(8), leaving the K-DMA in flight through PV)
    long vf0[8], vf1[8];
    {
      const u8* vtile = vbase + ((size_t)j << 15);
      #pragma unroll
      for (int ct = 0; ct < 8; ct++){
        int ch = 128*w + ct*16 + l15;
        int swz = ch & 7;
        const u8* vr = vtile + (size_t)ch*64;
        vf0[ct] = *(const long*)(vr + ((q4 ^ swz) << 3));
        vf1[ct] = *(const long*)(vr + (((4 + q4) ^ swz) << 3));
      }
    }
    // 2. issue DMA for K tile j+1 (other buffer; drains at end-of-iter sync)
    {
      const u8* kn = kbase + ((size_t)((j + 1) & 63) << 15);
      u8* kd = Kb[(j + 1) & 1];
      #pragma unroll
      for (int i = 0; i < 8; i++){
        int ci = i*256 + t;
        gload16(kn + (size_t)ci*16, kd + ci*16);
      }
    }
    // 3. S^T = K Q^T (fp8, swapped operands): 4 independent chains.
    //    Lane (q4,l15) accumulates S[q=rt*16+l15][kv=chh*32(+16)+q4*4+r].
    const u8* Kp = Kb[j & 1];
    f32x4 sA0, sA1, sB0, sB1;
    sA0[0]=0.f;sA0[1]=0.f;sA0[2]=0.f;sA0[3]=0.f;
    sA1[0]=0.f;sA1[1]=0.f;sA1[2]=0.f;sA1[3]=0.f;
    sB0[0]=0.f;sB0[1]=0.f;sB0[2]=0.f;sB0[3]=0.f;
    sB1[0]=0.f;sB1[1]=0.f;sB1[2]=0.f;sB1[3]=0.f;
    #pragma unroll
    for (int k2 = 0; k2 < 8; k2++){
      const u8* e0 = Kp + (2*k2)*2048;
      const u8* e1 = Kp + (2*k2 + 1)*2048;
      long ka0 = *(const long*)(e0 + ko0);
      long kb0 = *(const long*)(e0 + ko1);
      long ka1 = *(const long*)(e1 + ko0);
      long kb1 = *(const long*)(e1 + ko1);
      sA0 = __builtin_amdgcn_mfma_f32_16x16x32_fp8_fp8(ka0, qf[2*k2],   sA0, 0, 0, 0);
      sB0 = __builtin_amdgcn_mfma_f32_16x16x32_fp8_fp8(kb0, qf[2*k2],   sB0, 0, 0, 0);
      sA1 = __builtin_amdgcn_mfma_f32_16x16x32_fp8_fp8(ka1, qf[2*k2+1], sA1, 0, 0, 0);
      sB1 = __builtin_amdgcn_mfma_f32_16x16x32_fp8_fp8(kb1, qf[2*k2+1], sB1, 0, 0, 0);
    }
    // 4. max-free softmax -> P fp8 in LDS (packed u32 writes)
    {
      float a0 = __expf((sA0[0] + sA1[0]) * SCALE_Q);
      float a1 = __expf((sA0[1] + sA1[1]) * SCALE_Q);
      float a2 = __expf((sA0[2] + sA1[2]) * SCALE_Q);
      float a3 = __expf((sA0[3] + sA1[3]) * SCALE_Q);
      float b0 = __expf((sB0[0] + sB1[0]) * SCALE_Q);
      float b1 = __expf((sB0[1] + sB1[1]) * SCALE_Q);
      float b2 = __expf((sB0[2] + sB1[2]) * SCALE_Q);
      float b3 = __expf((sB0[3] + sB1[3]) * SCALE_Q);
      lrow += ((a0 + a1) + (a2 + a3)) + ((b0 + b1) + (b2 + b3));
      u8* Pw = Pb + (rt*16 + l15)*72 + chh*32 + q4*4;
      *(u32*)(Pw)      = pk4e4(a0, a1, a2, a3);
      *(u32*)(Pw + 16) = pk4e4(b0, b1, b2, b3);
    }
    BAR();                                   // P visible; DMA + vf in flight
    // 5. PV (fp8): O += P V ; wave owns col strip [128w, 128w+128)
    {
      long pf00 = *(const long*)(Pb + l15*72 + q4*8);
      long pf01 = *(const long*)(Pb + l15*72 + 32 + q4*8);
      long pf10 = *(const long*)(Pb + (16 + l15)*72 + q4*8);
      long pf11 = *(const long*)(Pb + (16 + l15)*72 + 32 + q4*8);
      #pragma unroll
      for (int ct = 0; ct < 8; ct++){
        f32x4 a0 = oacc[0][ct], a1 = oacc[1][ct];
        a0 = __builtin_amdgcn_mfma_f32_16x16x32_fp8_fp8(pf00, vf0[ct], a0, 0, 0, 0);
        a1 = __builtin_amdgcn_mfma_f32_16x16x32_fp8_fp8(pf10, vf0[ct], a1, 0, 0, 0);
        a0 = __builtin_amdgcn_mfma_f32_16x16x32_fp8_fp8(pf01, vf1[ct], a0, 0, 0, 0);
        a1 = __builtin_amdgcn_mfma_f32_16x16x32_fp8_fp8(pf11, vf1[ct], a1, 0, 0, 0);
        oacc[0][ct] = a0; oacc[1][ct] = a1;
      }
    }
    __syncthreads();                         // drains DMA(j+1) before S(j+1)
  }

  // ---- epilogue: reduce l across q4 groups + the two col-half waves ----
  {
    float v = lrow;
    v += __shfl_xor(v, 16);
    v += __shfl_xor(v, 32);
    if (ln < 16) lL[chh*32 + rt*16 + ln] = v;
  }
  __syncthreads();
  #pragma unroll
  for (int rr = 0; rr < 2; rr++){
    #pragma unroll
    for (int r = 0; r < 4; r++){
      int row = rr*16 + q4*4 + r;
      float inv = 1.f / (lL[row] + lL[32 + row]);
      u16* op = outO + ((size_t)b << 21) + (size_t)(q0 + row)*512 + 128*w + l15;
      #pragma unroll
      for (int ct = 0; ct < 8; ct++)
        op[ct*16] = f2b(oacc[rr][ct][r] * inv);
    }
  }
}

extern "C" void kernel_launch(void* const* d_in, const int* in_sizes, int n_in,
                              void* d_out, int out_size, void* d_ws, size_t ws_size,
                              hipStream_t stream){
  const float* x     = (const float*)d_in[0];
  const float* gamma = (const float*)d_in[1];
  const float* beta  = (const float*)d_in[2];
  const float* wq_w  = (const float*)d_in[3];
  const float* wq_b  = (const float*)d_in[4];
  const float* wk_w  = (const float*)d_in[5];
  const float* wk_b  = (const float*)d_in[6];
  const float* wv_w  = (const float*)d_in[7];
  const float* wv_b  = (const float*)d_in[8];
  const float* out_w = (const float*)d_in[9];
  const float* out_b = (const float*)d_in[10];

  char* ws = (char*)d_ws;
  float* stats = (float*)ws;                                   // 1 KB
  u16* tbuf = (u16*)(ws + 4096);                               // 16 MB (t, then O)
  size_t off = 4096 + (size_t)16*1024*1024;
  u16* Wcat = (u16*)(ws + off); off += (size_t)4*512*512*2;    // 2 MB
  u8*  qb   = (u8*)(ws + off);  off += (size_t)16*1024*1024;   // Q fp8
  u8*  ktb  = (u8*)(ws + off);  off += (size_t)16*1024*1024;   // K fp8 tiled
  u8*  vtb  = (u8*)(ws + off);  off += (size_t)16*1024*1024;   // V fp8 tiled

  gn_stats<<<128, 256, 0, stream>>>(x, stats);
  gn_apply_T<<<dim3(128, 16, 4), 256, 0, stream>>>(x, stats, gamma, beta, tbuf);
  w2bf<<<1024, 256, 0, stream>>>(wq_w, wk_w, wv_w, out_w, Wcat);
  u16* Wo = Wcat + 3*512*512;
  qkv_gemm<<<dim3(128, 12), 256, 0, stream>>>(tbuf, Wcat, wq_b, wk_b, wv_b,
                                              qb, ktb, vtb);
  attn_fwd<<<dim3(128, 4), 256, 0, stream>>>(qb, ktb, vtb, tbuf);
  out_gemm<<<dim3(128, 4), 256, 0, stream>>>(tbuf, Wo, out_b, (float*)d_out, x);
}